// Round 5
// baseline (609.600 us; speedup 1.0000x reference)
//
#include <hip/hip_runtime.h>
#include <hip/hip_bf16.h>

#define NEG_SLOPE 0.2f

typedef _Float16 f16x8 __attribute__((ext_vector_type(8)));
typedef _Float16 f16x4 __attribute__((ext_vector_type(4)));
typedef float f32x4 __attribute__((ext_vector_type(4)));
typedef unsigned short ushort_t;

#define AS_GLOBAL(p) ((const __attribute__((address_space(1))) void*)(p))
#define AS_SHARED(p) ((__attribute__((address_space(3))) void*)(p))

__device__ inline f16x4 cvt4(float4 v) {
    f16x4 r;
    r[0] = (_Float16)v.x; r[1] = (_Float16)v.y;
    r[2] = (_Float16)v.z; r[3] = (_Float16)v.w;
    return r;
}

// ---------------------------------------------------------------------------
// L1: dst-histogram (blocks [0,HB)) ∪ weight prep (blocks [HB,HB+640)).
// Independent work merged into one launch for concurrency.
// W_pre/W1 -> fp16, swizzled to MFMA-B-frag order:
// elem (k,n) -> ((k>>3)*Nn + n)*8 + (k&7).
// ---------------------------------------------------------------------------
__global__ __launch_bounds__(256) void kl1(const int* __restrict__ edst, int E,
                                           int* __restrict__ counts,
                                           const float* __restrict__ Wpre,
                                           const float* __restrict__ W1,
                                           ushort_t* __restrict__ PreF,
                                           ushort_t* __restrict__ W1h, int HB) {
    int b = blockIdx.x, t = threadIdx.x;
    if (b < HB) {
        int i = b * 256 + t;
        if (i < E) atomicAdd(&counts[edst[i]], 1);
    } else {
        int i = (b - HB) * 256 + t;
        if (i < 1024 * 128) {
            int k = i >> 7, n = i & 127;
            int d = ((k >> 3) * 128 + n) * 8 + (k & 7);
            PreF[d] = __builtin_bit_cast(ushort_t, (_Float16)Wpre[i]);
        } else if (i < 1024 * 128 + 128 * 256) {
            int j2 = i - 1024 * 128;
            int k = j2 >> 8, n = j2 & 255;
            int d = ((k >> 3) * 256 + n) * 8 + (k & 7);
            W1h[d] = __builtin_bit_cast(ushort_t, (_Float16)W1[j2]);
        }
    }
}

// ---------------------------------------------------------------------------
// L2: block 0 = single-block exclusive scan of (counts[i]+1) -> row_ptr/cursor
//     blocks 1.. = GEMM1: h0h(fp16) = relu(x @ W_pre + b_pre). M x 1024 x 128.
// GEMM1: M-tile 32, 4 waves = 2 row-halves x 2 col-halves. A staged
// cooperatively: coalesced float4 loads -> fp16 cvt -> XOR-swizzled LDS
// (chunk c of row r stored at chunk (c ^ (r & 7))). B via global_load_lds
// from pre-swizzled global.
// ---------------------------------------------------------------------------
__global__ __launch_bounds__(256) void kl2(const float* __restrict__ A,
                                           const ushort_t* __restrict__ Bf,
                                           const float* __restrict__ bias,
                                           ushort_t* __restrict__ C, int M,
                                           const int* __restrict__ counts,
                                           int* __restrict__ row_ptr,
                                           int* __restrict__ cursor) {
    __shared__ __align__(16) ushort_t Bs[8192];   // 16 KB: B K-tile [kc8][n128][j8]
    __shared__ __align__(16) ushort_t As[2048];   // 4 KB: A tile 32x64 fp16, swizzled
    __shared__ int wsum2[4];
    int t = threadIdx.x;

    if (blockIdx.x == 0) {
        // ---- single-block scan: each thread owns a contiguous chunk ----
        int CH = (M + 255) >> 8;
        int lo = t * CH, hi = min(lo + CH, M);
        int s = 0;
        for (int i = lo; i < hi; ++i) s += counts[i] + 1;
        int lane = t & 63, wid = t >> 6;
        int x = s;
        #pragma unroll
        for (int off = 1; off < 64; off <<= 1) {
            int y = __shfl_up(x, off, 64);
            if (lane >= off) x += y;
        }
        if (lane == 63) wsum2[wid] = x;
        __syncthreads();
        int wof = 0;
        #pragma unroll
        for (int w = 0; w < 3; ++w) if (wid > w) wof += wsum2[w];
        int run = wof + x - s;   // exclusive prefix across the block
        for (int i = lo; i < hi; ++i) {
            row_ptr[i] = run;
            cursor[i] = run;
            run += counts[i] + 1;
        }
        if (lo < M && hi == M) row_ptr[M] = run;
        return;
    }

    // ---- GEMM1 ----
    int wid = t >> 6, lane = t & 63, q = lane >> 4, l15 = lane & 15;
    int wr = wid & 1, wc = wid >> 1;
    int m0 = (blockIdx.x - 1) * 32;

    int ar = t >> 3, ac = t & 7;
    int srow = m0 + ar;
    if (srow >= M) srow = M - 1;
    const float* sA = A + (size_t)srow * 1024;
    int sw = ar & 7;                              // write-side XOR (row mod 8)
    int wadr0 = ar * 64 + (((ac >> 1)) ^ sw) * 8 + (ac & 1) * 4;
    int wadr1 = ar * 64 + ((4 + (ac >> 1)) ^ sw) * 8 + (ac & 1) * 4;

    float4 av[2][2];
    av[0][0] = *(const float4*)(sA + ac * 4);
    av[0][1] = *(const float4*)(sA + 32 + ac * 4);

    f32x4 acc[4];
    #pragma unroll
    for (int c = 0; c < 4; ++c) acc[c] = (f32x4){0.f, 0.f, 0.f, 0.f};

    int arow_rd = (wr * 16 + l15) * 64;
    int asw = l15 & 7;                            // read-side XOR (row mod 8)

    #pragma unroll 2
    for (int kt = 0; kt < 16; ++kt) {
        int cur = kt & 1, nxt = cur ^ 1;
        __syncthreads();
        {   // B-tile kt -> LDS (async DMA)
            const ushort_t* sF = Bf + kt * 8192;
            #pragma unroll
            for (int i = 0; i < 4; ++i) {
                int ge = (i * 256 + t) * 8;
                int le = (i * 256 + (t & 0xC0)) * 8;
                __builtin_amdgcn_global_load_lds(AS_GLOBAL(sF + ge), AS_SHARED(Bs + le), 16, 0, 0);
            }
        }
        if (kt < 15) {
            const float* a2 = sA + (kt + 1) * 64;
            av[nxt][0] = *(const float4*)(a2 + ac * 4);
            av[nxt][1] = *(const float4*)(a2 + 32 + ac * 4);
        }
        *(f16x4*)(As + wadr0) = cvt4(av[cur][0]);
        *(f16x4*)(As + wadr1) = cvt4(av[cur][1]);
        __syncthreads();
        #pragma unroll
        for (int ks = 0; ks < 2; ++ks) {
            int kc = ks * 4 + q;
            f16x8 af = *(const f16x8*)(As + arow_rd + ((kc ^ asw) * 8));
            #pragma unroll
            for (int c = 0; c < 4; ++c) {
                f16x8 b = *(const f16x8*)(Bs + (kc * 128 + wc * 64 + c * 16 + l15) * 8);
                acc[c] = __builtin_amdgcn_mfma_f32_16x16x32_f16(af, b, acc[c], 0, 0, 0);
            }
        }
    }
    #pragma unroll
    for (int c = 0; c < 4; ++c) {
        int n = wc * 64 + c * 16 + l15;
        float bv = bias[n];
        #pragma unroll
        for (int r = 0; r < 4; ++r) {
            int mm = m0 + wr * 16 + q * 4 + r;
            if (mm < M)
                C[(size_t)mm * 128 + n] =
                    __builtin_bit_cast(ushort_t, (_Float16)fmaxf(acc[c][r] + bv, 0.f));
        }
    }
}

// ---------------------------------------------------------------------------
// L3: CSR fill (blocks [0,FB)) ∪ GEMM2+alpha1 (blocks [FB, FB+2*Mb)).
// GEMM2: h1h(fp16) = h0h @ W1h, f16 MFMA; 64 rows x 128 cols per block,
// g = column half = head; fused as1/ad1 epilogue.
// ---------------------------------------------------------------------------
__global__ __launch_bounds__(256) void kl3(const int* __restrict__ esrc,
                                           const int* __restrict__ edst, int E, int n,
                                           int* __restrict__ cursor,
                                           int* __restrict__ edge_src, int FB,
                                           const ushort_t* __restrict__ Ah,
                                           const ushort_t* __restrict__ W1h,
                                           const float* __restrict__ a_src,
                                           const float* __restrict__ a_dst,
                                           ushort_t* __restrict__ C,
                                           float* __restrict__ as1,
                                           float* __restrict__ ad1, int M) {
    __shared__ __align__(16) ushort_t Bs[16384];  // [kc16][n128][j8] fp16 = 32 KB
    int t = threadIdx.x;
    int b = blockIdx.x;
    if (b < FB) {
        int i = b * 256 + t;
        if (i < E) {
            int p = atomicAdd(&cursor[edst[i]], 1);
            edge_src[p] = esrc[i];
        } else if (i < E + n) {
            int v = i - E;
            int p = atomicAdd(&cursor[v], 1);
            edge_src[p] = v;
        }
        return;
    }
    int u = b - FB;
    int g = u & 1;
    int mblk = u >> 1;
    int wid = t >> 6, lane = t & 63;
    int q = lane >> 4, l15 = lane & 15;
    int m0 = mblk * 64 + wid * 16;
    int m = m0 + l15;
    const ushort_t* arow = Ah + (size_t)(m < M ? m : 0) * 128;

    {   // stage W1h half (cols g*128..+127)
        #pragma unroll
        for (int i = 0; i < 8; ++i) {
            int j = i * 4 + wid;
            int kc = j >> 1, hk = j & 1;
            int ge = ((kc * 256) + g * 128 + hk * 64 + lane) * 8;
            int le = j * 512;
            __builtin_amdgcn_global_load_lds(AS_GLOBAL(W1h + ge), AS_SHARED(Bs + le), 16, 0, 0);
        }
    }
    f16x8 af[4];
    #pragma unroll
    for (int ks = 0; ks < 4; ++ks)
        af[ks] = *(const f16x8*)(arow + ks * 32 + q * 8);
    __syncthreads();

    f32x4 acc[8];
    #pragma unroll
    for (int c = 0; c < 8; ++c) acc[c] = (f32x4){0.f, 0.f, 0.f, 0.f};

    #pragma unroll
    for (int ks = 0; ks < 4; ++ks) {
        int kc = ks * 4 + q;
        #pragma unroll
        for (int c = 0; c < 8; ++c) {
            f16x8 bfr = *(const f16x8*)(Bs + (kc * 128 + c * 16 + l15) * 8);
            acc[c] = __builtin_amdgcn_mfma_f32_16x16x32_f16(af[ks], bfr, acc[c], 0, 0, 0);
        }
    }
    #pragma unroll
    for (int c = 0; c < 8; ++c) {
        int nn = g * 128 + c * 16 + l15;
        #pragma unroll
        for (int r = 0; r < 4; ++r) {
            int mm = m0 + q * 4 + r;
            if (mm < M)
                C[(size_t)mm * 256 + nn] = __builtin_bit_cast(ushort_t, (_Float16)acc[c][r]);
        }
    }
    float asv[4] = {0.f, 0.f, 0.f, 0.f};
    float adv[4] = {0.f, 0.f, 0.f, 0.f};
    #pragma unroll
    for (int c = 0; c < 8; ++c) {
        float sa = a_src[g * 128 + c * 16 + l15];
        float da = a_dst[g * 128 + c * 16 + l15];
        #pragma unroll
        for (int r = 0; r < 4; ++r) {
            asv[r] += acc[c][r] * sa;
            adv[r] += acc[c][r] * da;
        }
    }
    #pragma unroll
    for (int off = 1; off <= 8; off <<= 1) {
        #pragma unroll
        for (int r = 0; r < 4; ++r) {
            asv[r] += __shfl_xor(asv[r], off, 64);
            adv[r] += __shfl_xor(adv[r], off, 64);
        }
    }
    if (l15 == 0) {
        #pragma unroll
        for (int r = 0; r < 4; ++r) {
            int node = m0 + q * 4 + r;
            if (node < M) {
                as1[node * 2 + g] = asv[r];
                ad1[node * 2 + g] = adv[r];
            }
        }
    }
}

// ---------------------------------------------------------------------------
// Aggregation layer 1 + fused layer-2 linear + alpha2.
// Wave-per-node, barrier-free, LDS-free.
// ---------------------------------------------------------------------------
__global__ __launch_bounds__(256) void kagg1(const ushort_t* __restrict__ h1h,
                                             const float* __restrict__ as1,
                                             const float* __restrict__ ad1,
                                             const float* __restrict__ b1,
                                             const float* __restrict__ W2,
                                             const float* __restrict__ a_src2,
                                             const float* __restrict__ a_dst2,
                                             const int* __restrict__ row_ptr,
                                             const int* __restrict__ edge_src,
                                             float* __restrict__ h2,
                                             float* __restrict__ as2,
                                             float* __restrict__ ad2, int n) {
    int wid = threadIdx.x >> 6, lane = threadIdx.x & 63;
    int node = blockIdx.x * 4 + wid;
    if (node >= n) return;
    int beg = row_ptr[node], end = row_ptr[node + 1];
    int h = lane >> 5;                       // head of my 4 channels
    float adv0 = ad1[node * 2];
    float adv1 = ad1[node * 2 + 1];
    float acc0 = 0.f, acc1 = 0.f, acc2 = 0.f, acc3 = 0.f, ssum = 0.f;
    for (int base = beg; base < end; base += 32) {
        int cnt = min(32, end - base);
        float wv_mine = 0.f;
        int s_mine = 0;
        {
            int i = lane >> 1, hh = lane & 1;
            if (i < cnt) {
                s_mine = edge_src[base + i];
                float e = as1[s_mine * 2 + hh] + (hh ? adv1 : adv0);
                e = (e > 0.f) ? e : NEG_SLOPE * e;
                wv_mine = __expf(e);
            }
        }
        #pragma unroll 4
        for (int i2 = 0; i2 < cnt; ++i2) {
            int s = __shfl(s_mine, i2 * 2, 64);
            float wv = __shfl(wv_mine, i2 * 2 + h, 64);
            uint2 p = *(const uint2*)(h1h + (size_t)s * 256 + lane * 4);
            acc0 += wv * (float)__builtin_bit_cast(_Float16, (ushort_t)(p.x & 0xffffu));
            acc1 += wv * (float)__builtin_bit_cast(_Float16, (ushort_t)(p.x >> 16));
            acc2 += wv * (float)__builtin_bit_cast(_Float16, (ushort_t)(p.y & 0xffffu));
            acc3 += wv * (float)__builtin_bit_cast(_Float16, (ushort_t)(p.y >> 16));
            ssum += wv;
        }
    }
    float inv = 1.f / (ssum + 1e-16f);
    float o0 = acc0 * inv + b1[lane * 4 + 0];
    float o1 = acc1 * inv + b1[lane * 4 + 1];
    float o2 = acc2 * inv + b1[lane * 4 + 2];
    float o3 = acc3 * inv + b1[lane * 4 + 3];
    o0 = (o0 > 0.f) ? o0 : (__expf(o0) - 1.f);
    o1 = (o1 > 0.f) ? o1 : (__expf(o1) - 1.f);
    o2 = (o2 > 0.f) ? o2 : (__expf(o2) - 1.f);
    o3 = (o3 > 0.f) ? o3 : (__expf(o3) - 1.f);
    float4 w0 = *(const float4*)(W2 + (lane * 4 + 0) * 4);
    float4 w1 = *(const float4*)(W2 + (lane * 4 + 1) * 4);
    float4 w2 = *(const float4*)(W2 + (lane * 4 + 2) * 4);
    float4 w3 = *(const float4*)(W2 + (lane * 4 + 3) * 4);
    float p0 = o0 * w0.x + o1 * w1.x + o2 * w2.x + o3 * w3.x;
    float p1 = o0 * w0.y + o1 * w1.y + o2 * w2.y + o3 * w3.y;
    float p2 = o0 * w0.z + o1 * w1.z + o2 * w2.z + o3 * w3.z;
    float p3 = o0 * w0.w + o1 * w1.w + o2 * w2.w + o3 * w3.w;
    #pragma unroll
    for (int off = 1; off < 64; off <<= 1) {
        p0 += __shfl_xor(p0, off, 64);
        p1 += __shfl_xor(p1, off, 64);
        p2 += __shfl_xor(p2, off, 64);
        p3 += __shfl_xor(p3, off, 64);
    }
    if (lane == 0) {
        h2[node * 4 + 0] = p0;
        h2[node * 4 + 1] = p1;
        h2[node * 4 + 2] = p2;
        h2[node * 4 + 3] = p3;
        as2[node] = p0 * a_src2[0] + p1 * a_src2[1] + p2 * a_src2[2] + p3 * a_src2[3];
        ad2[node] = p0 * a_dst2[0] + p1 * a_dst2[1] + p2 * a_dst2[2] + p3 * a_dst2[3];
    }
}

// ---------------------------------------------------------------------------
// Aggregation layer 2 (1 head, C=4): wave per node, 16 edges in flight.
// ---------------------------------------------------------------------------
__global__ __launch_bounds__(256) void kagg2(const float* __restrict__ h2,
                                             const float* __restrict__ as2,
                                             const float* __restrict__ ad2,
                                             const float* __restrict__ b2,
                                             const int* __restrict__ row_ptr,
                                             const int* __restrict__ edge_src,
                                             float* __restrict__ out, int n) {
    int wid = threadIdx.x >> 6, lane = threadIdx.x & 63;
    int node = blockIdx.x * 4 + wid;
    if (node >= n) return;
    int beg = row_ptr[node], end = row_ptr[node + 1];
    int j = lane & 3, ig = lane >> 2;
    float adv = ad2[node];
    float acc = 0.f, ssum = 0.f;
    for (int p = beg + ig; p < end; p += 16) {
        int s = edge_src[p];
        float e = as2[s] + adv;
        e = (e > 0.f) ? e : NEG_SLOPE * e;
        float wv = __expf(e);
        acc += wv * h2[s * 4 + j];
        ssum += wv;
    }
    #pragma unroll
    for (int off = 32; off >= 4; off >>= 1) {
        acc += __shfl_down(acc, off);
        ssum += __shfl_down(ssum, off);
    }
    if (lane < 4) out[node * 4 + j] = acc / (ssum + 1e-16f) + b2[j];
}

// ---------------------------------------------------------------------------
extern "C" void kernel_launch(void* const* d_in, const int* in_sizes, int n_in,
                              void* d_out, int out_size, void* d_ws, size_t ws_size,
                              hipStream_t stream) {
    const float* x      = (const float*)d_in[0];
    const int*   ei     = (const int*)d_in[1];
    const float* W_pre  = (const float*)d_in[2];
    const float* b_pre  = (const float*)d_in[3];
    const float* W1     = (const float*)d_in[4];
    const float* a_src1 = (const float*)d_in[5];
    const float* a_dst1 = (const float*)d_in[6];
    const float* b1     = (const float*)d_in[7];
    const float* W2     = (const float*)d_in[8];
    const float* a_src2 = (const float*)d_in[9];
    const float* a_dst2 = (const float*)d_in[10];
    const float* b2     = (const float*)d_in[11];
    float* out = (float*)d_out;

    const int DIN = 1024;
    const int E = in_sizes[1] / 2;
    const int N = in_sizes[0] / DIN;

    const int* esrc = ei;
    const int* edst = ei + E;

    char* ws = (char*)d_ws;
    size_t off = 0;
    ushort_t* h1h = (ushort_t*)(ws + off); off += (size_t)N * 256 * 2;
    ushort_t* h0h = (ushort_t*)(ws + off); off += (size_t)N * 128 * 2;
    float* as1 = (float*)(ws + off);  off += (size_t)N * 2 * 4;
    float* ad1 = (float*)(ws + off);  off += (size_t)N * 2 * 4;
    float* h2  = (float*)(ws + off);  off += (size_t)N * 4 * 4;
    float* as2 = (float*)(ws + off);  off += (size_t)N * 4;
    float* ad2 = (float*)(ws + off);  off += (size_t)N * 4;
    int* row_ptr = (int*)(ws + off);  off += ((size_t)N + 16) * 4;
    int* cursor  = (int*)(ws + off);  off += (size_t)N * 4;
    int* counts  = (int*)(ws + off);  off += (size_t)N * 4;
    int* edge_src = (int*)(ws + off); off += (size_t)(E + N) * 4;
    ushort_t* PreF = (ushort_t*)(ws + off); off += 1024 * 128 * 2;
    ushort_t* W1h  = (ushort_t*)(ws + off); off += 128 * 256 * 2;

    // --- L0: zero counts ---
    hipMemsetAsync(counts, 0, (size_t)N * 4, stream);

    // --- L1: dst histogram ∪ weight prep ---
    int HB = (E + 255) / 256;
    kl1<<<HB + 640, 256, 0, stream>>>(edst, E, counts, W_pre, W1, PreF, W1h, HB);

    // --- L2: single-block scan ∪ GEMM1 ---
    int Mb32 = (N + 31) / 32;
    kl2<<<1 + Mb32, 256, 0, stream>>>(x, PreF, b_pre, h0h, N, counts, row_ptr, cursor);

    // --- L3: CSR fill ∪ GEMM2+alpha1 ---
    int FB = (E + N + 255) / 256;
    int Mb = (N + 63) / 64;
    kl3<<<FB + 2 * Mb, 256, 0, stream>>>(esrc, edst, E, N, cursor, edge_src, FB,
                                         h0h, W1h, a_src1, a_dst1, h1h, as1, ad1, N);

    // --- aggregate layer 1 + bias + elu + layer-2 linear + alpha2 (fused) ---
    kagg1<<<(N + 3) / 4, 256, 0, stream>>>(h1h, as1, ad1, b1, W2, a_src2, a_dst2,
                                           row_ptr, edge_src, h2, as2, ad2, N);
    // --- aggregate layer 2 + bias -> out ---
    kagg2<<<(N + 3) / 4, 256, 0, stream>>>(h2, as2, ad2, b2, row_ptr, edge_src, out, N);
}

// Round 6
// 527.856 us; speedup vs baseline: 1.1549x; 1.1549x over previous
//
#include <hip/hip_runtime.h>
#include <hip/hip_bf16.h>

#define NEG_SLOPE 0.2f

typedef _Float16 f16x8 __attribute__((ext_vector_type(8)));
typedef _Float16 f16x4 __attribute__((ext_vector_type(4)));
typedef float f32x4 __attribute__((ext_vector_type(4)));
typedef unsigned short ushort_t;

#define AS_GLOBAL(p) ((const __attribute__((address_space(1))) void*)(p))
#define AS_SHARED(p) ((__attribute__((address_space(3))) void*)(p))

__device__ inline f16x4 cvt4(float4 v) {
    f16x4 r;
    r[0] = (_Float16)v.x; r[1] = (_Float16)v.y;
    r[2] = (_Float16)v.z; r[3] = (_Float16)v.w;
    return r;
}

// ---------------------------------------------------------------------------
// L1: dst-histogram (blocks [0,HB)) ∪ weight prep (blocks [HB,HB+640)).
// W_pre/W1 -> fp16, swizzled to MFMA-B-frag order:
// elem (k,n) -> ((k>>3)*Nn + n)*8 + (k&7).
// ---------------------------------------------------------------------------
__global__ __launch_bounds__(256) void kl1(const int* __restrict__ edst, int E,
                                           int* __restrict__ counts,
                                           const float* __restrict__ Wpre,
                                           const float* __restrict__ W1,
                                           ushort_t* __restrict__ PreF,
                                           ushort_t* __restrict__ W1h, int HB) {
    int b = blockIdx.x, t = threadIdx.x;
    if (b < HB) {
        int i = b * 256 + t;
        if (i < E) atomicAdd(&counts[edst[i]], 1);
    } else {
        int i = (b - HB) * 256 + t;
        if (i < 1024 * 128) {
            int k = i >> 7, n = i & 127;
            int d = ((k >> 3) * 128 + n) * 8 + (k & 7);
            PreF[d] = __builtin_bit_cast(ushort_t, (_Float16)Wpre[i]);
        } else if (i < 1024 * 128 + 128 * 256) {
            int j2 = i - 1024 * 128;
            int k = j2 >> 8, n = j2 & 255;
            int d = ((k >> 3) * 256 + n) * 8 + (k & 7);
            W1h[d] = __builtin_bit_cast(ushort_t, (_Float16)W1[j2]);
        }
    }
}

// ---------------------------------------------------------------------------
// Parallel scan (3 small kernels, coalesced): counts(+1 self-loop) -> row_ptr
// ---------------------------------------------------------------------------
__global__ __launch_bounds__(1024) void kscan_part(const int* __restrict__ counts,
                                                   int* __restrict__ row_ptr,
                                                   int* __restrict__ bsum, int n) {
    __shared__ int wsum[16];
    int t = threadIdx.x, lane = t & 63, wid = t >> 6;
    int i = blockIdx.x * 1024 + t;
    int v = (i < n) ? (counts[i] + 1) : 0;
    int x = v;
    #pragma unroll
    for (int off = 1; off < 64; off <<= 1) {
        int y = __shfl_up(x, off, 64);
        if (lane >= off) x += y;
    }
    if (lane == 63) wsum[wid] = x;
    __syncthreads();
    if (wid == 0) {
        int ws = (lane < 16) ? wsum[lane] : 0;
        #pragma unroll
        for (int off = 1; off < 16; off <<= 1) {
            int y = __shfl_up(ws, off, 64);
            if (lane >= off) ws += y;
        }
        if (lane < 16) wsum[lane] = ws;
    }
    __syncthreads();
    int wave_excl = (wid == 0) ? 0 : wsum[wid - 1];
    if (i < n) row_ptr[i] = wave_excl + (x - v);
    if (t == 0) bsum[blockIdx.x] = wsum[15];
}

__global__ void kscan_tops(const int* __restrict__ bsum, int* __restrict__ boff,
                           int* __restrict__ row_ptr, int G, int n) {
    int lane = threadIdx.x;
    int v = (lane < G) ? bsum[lane] : 0;
    int x = v;
    #pragma unroll
    for (int off = 1; off < 64; off <<= 1) {
        int y = __shfl_up(x, off, 64);
        if (lane >= off) x += y;
    }
    if (lane < G) boff[lane] = x - v;
    if (lane == 63) row_ptr[n] = x;
}

__global__ void kscan_add(int* __restrict__ row_ptr, const int* __restrict__ boff,
                          int* __restrict__ cursor, int n) {
    int i = blockIdx.x * blockDim.x + threadIdx.x;
    if (i < n) {
        int r = row_ptr[i] + boff[i >> 10];
        row_ptr[i] = r;
        cursor[i] = r;
    }
}

// ---------------------------------------------------------------------------
// GEMM1: h0h(fp16) = relu(x @ W_pre + b_pre).  M x 1024 x 128.
// M-tile 32, 4 waves = 2 row-halves x 2 col-halves. A staged cooperatively:
// coalesced float4 loads -> fp16 cvt -> XOR-swizzled LDS (chunk c of row r
// stored at chunk (c ^ (r & 7))). B via global_load_lds (pre-swizzled).
// ---------------------------------------------------------------------------
__global__ __launch_bounds__(256) void kgemm_mfma1(const float* __restrict__ A,
                                                   const ushort_t* __restrict__ Bf,
                                                   const float* __restrict__ bias,
                                                   ushort_t* __restrict__ C, int M) {
    __shared__ __align__(16) ushort_t Bs[8192];   // 16 KB: B K-tile [kc8][n128][j8]
    __shared__ __align__(16) ushort_t As[2048];   // 4 KB: A tile 32x64 fp16, swizzled
    int t = threadIdx.x;
    int wid = t >> 6, lane = t & 63, q = lane >> 4, l15 = lane & 15;
    int wr = wid & 1, wc = wid >> 1;
    int m0 = blockIdx.x * 32;

    int ar = t >> 3, ac = t & 7;
    int srow = m0 + ar;
    if (srow >= M) srow = M - 1;
    const float* sA = A + (size_t)srow * 1024;
    int sw = ar & 7;                              // write-side XOR (row mod 8)
    int wadr0 = ar * 64 + (((ac >> 1)) ^ sw) * 8 + (ac & 1) * 4;
    int wadr1 = ar * 64 + ((4 + (ac >> 1)) ^ sw) * 8 + (ac & 1) * 4;

    float4 av[2][2];
    av[0][0] = *(const float4*)(sA + ac * 4);
    av[0][1] = *(const float4*)(sA + 32 + ac * 4);

    f32x4 acc[4];
    #pragma unroll
    for (int c = 0; c < 4; ++c) acc[c] = (f32x4){0.f, 0.f, 0.f, 0.f};

    int arow_rd = (wr * 16 + l15) * 64;
    int asw = l15 & 7;                            // read-side XOR (row mod 8)

    #pragma unroll 2
    for (int kt = 0; kt < 16; ++kt) {
        int cur = kt & 1, nxt = cur ^ 1;
        __syncthreads();
        {   // B-tile kt -> LDS (async DMA)
            const ushort_t* sF = Bf + kt * 8192;
            #pragma unroll
            for (int i = 0; i < 4; ++i) {
                int ge = (i * 256 + t) * 8;
                int le = (i * 256 + (t & 0xC0)) * 8;
                __builtin_amdgcn_global_load_lds(AS_GLOBAL(sF + ge), AS_SHARED(Bs + le), 16, 0, 0);
            }
        }
        if (kt < 15) {
            const float* a2 = sA + (kt + 1) * 64;
            av[nxt][0] = *(const float4*)(a2 + ac * 4);
            av[nxt][1] = *(const float4*)(a2 + 32 + ac * 4);
        }
        *(f16x4*)(As + wadr0) = cvt4(av[cur][0]);
        *(f16x4*)(As + wadr1) = cvt4(av[cur][1]);
        __syncthreads();
        #pragma unroll
        for (int ks = 0; ks < 2; ++ks) {
            int kc = ks * 4 + q;
            f16x8 af = *(const f16x8*)(As + arow_rd + ((kc ^ asw) * 8));
            #pragma unroll
            for (int c = 0; c < 4; ++c) {
                f16x8 b = *(const f16x8*)(Bs + (kc * 128 + wc * 64 + c * 16 + l15) * 8);
                acc[c] = __builtin_amdgcn_mfma_f32_16x16x32_f16(af, b, acc[c], 0, 0, 0);
            }
        }
    }
    #pragma unroll
    for (int c = 0; c < 4; ++c) {
        int n = wc * 64 + c * 16 + l15;
        float bv = bias[n];
        #pragma unroll
        for (int r = 0; r < 4; ++r) {
            int mm = m0 + wr * 16 + q * 4 + r;
            if (mm < M)
                C[(size_t)mm * 128 + n] =
                    __builtin_bit_cast(ushort_t, (_Float16)fmaxf(acc[c][r] + bv, 0.f));
        }
    }
}

// ---------------------------------------------------------------------------
// L3: CSR fill (blocks [0,FB)) ∪ GEMM2+alpha1 (blocks [FB, FB+2*Mb)).
// GEMM2: h1h(fp16) = h0h @ W1h, f16 MFMA; 64 rows x 128 cols per block,
// g = column half = head; fused as1/ad1 epilogue.
// ---------------------------------------------------------------------------
__global__ __launch_bounds__(256) void kl3(const int* __restrict__ esrc,
                                           const int* __restrict__ edst, int E, int n,
                                           int* __restrict__ cursor,
                                           int* __restrict__ edge_src, int FB,
                                           const ushort_t* __restrict__ Ah,
                                           const ushort_t* __restrict__ W1h,
                                           const float* __restrict__ a_src,
                                           const float* __restrict__ a_dst,
                                           ushort_t* __restrict__ C,
                                           float* __restrict__ as1,
                                           float* __restrict__ ad1, int M) {
    __shared__ __align__(16) ushort_t Bs[16384];  // [kc16][n128][j8] fp16 = 32 KB
    int t = threadIdx.x;
    int b = blockIdx.x;
    if (b < FB) {
        int i = b * 256 + t;
        if (i < E) {
            int p = atomicAdd(&cursor[edst[i]], 1);
            edge_src[p] = esrc[i];
        } else if (i < E + n) {
            int v = i - E;
            int p = atomicAdd(&cursor[v], 1);
            edge_src[p] = v;
        }
        return;
    }
    int u = b - FB;
    int g = u & 1;
    int mblk = u >> 1;
    int wid = t >> 6, lane = t & 63;
    int q = lane >> 4, l15 = lane & 15;
    int m0 = mblk * 64 + wid * 16;
    int m = m0 + l15;
    const ushort_t* arow = Ah + (size_t)(m < M ? m : 0) * 128;

    {   // stage W1h half (cols g*128..+127)
        #pragma unroll
        for (int i = 0; i < 8; ++i) {
            int j = i * 4 + wid;
            int kc = j >> 1, hk = j & 1;
            int ge = ((kc * 256) + g * 128 + hk * 64 + lane) * 8;
            int le = j * 512;
            __builtin_amdgcn_global_load_lds(AS_GLOBAL(W1h + ge), AS_SHARED(Bs + le), 16, 0, 0);
        }
    }
    f16x8 af[4];
    #pragma unroll
    for (int ks = 0; ks < 4; ++ks)
        af[ks] = *(const f16x8*)(arow + ks * 32 + q * 8);
    __syncthreads();

    f32x4 acc[8];
    #pragma unroll
    for (int c = 0; c < 8; ++c) acc[c] = (f32x4){0.f, 0.f, 0.f, 0.f};

    #pragma unroll
    for (int ks = 0; ks < 4; ++ks) {
        int kc = ks * 4 + q;
        #pragma unroll
        for (int c = 0; c < 8; ++c) {
            f16x8 bfr = *(const f16x8*)(Bs + (kc * 128 + c * 16 + l15) * 8);
            acc[c] = __builtin_amdgcn_mfma_f32_16x16x32_f16(af[ks], bfr, acc[c], 0, 0, 0);
        }
    }
    #pragma unroll
    for (int c = 0; c < 8; ++c) {
        int nn = g * 128 + c * 16 + l15;
        #pragma unroll
        for (int r = 0; r < 4; ++r) {
            int mm = m0 + q * 4 + r;
            if (mm < M)
                C[(size_t)mm * 256 + nn] = __builtin_bit_cast(ushort_t, (_Float16)acc[c][r]);
        }
    }
    float asv[4] = {0.f, 0.f, 0.f, 0.f};
    float adv[4] = {0.f, 0.f, 0.f, 0.f};
    #pragma unroll
    for (int c = 0; c < 8; ++c) {
        float sa = a_src[g * 128 + c * 16 + l15];
        float da = a_dst[g * 128 + c * 16 + l15];
        #pragma unroll
        for (int r = 0; r < 4; ++r) {
            asv[r] += acc[c][r] * sa;
            adv[r] += acc[c][r] * da;
        }
    }
    #pragma unroll
    for (int off = 1; off <= 8; off <<= 1) {
        #pragma unroll
        for (int r = 0; r < 4; ++r) {
            asv[r] += __shfl_xor(asv[r], off, 64);
            adv[r] += __shfl_xor(adv[r], off, 64);
        }
    }
    if (l15 == 0) {
        #pragma unroll
        for (int r = 0; r < 4; ++r) {
            int node = m0 + q * 4 + r;
            if (node < M) {
                as1[node * 2 + g] = asv[r];
                ad1[node * 2 + g] = adv[r];
            }
        }
    }
}

// ---------------------------------------------------------------------------
// Aggregation layer 1 + fused layer-2 linear + alpha2.
// 128-thread block per dst node; thread t owns channels 2t,2t+1 (head t>>6).
// ---------------------------------------------------------------------------
__global__ __launch_bounds__(128) void kagg1(const ushort_t* __restrict__ h1h,
                                             const float* __restrict__ as1,
                                             const float* __restrict__ ad1,
                                             const float* __restrict__ b1,
                                             const float* __restrict__ W2,
                                             const float* __restrict__ a_src2,
                                             const float* __restrict__ a_dst2,
                                             const int* __restrict__ row_ptr,
                                             const int* __restrict__ edge_src,
                                             float* __restrict__ h2,
                                             float* __restrict__ as2,
                                             float* __restrict__ ad2, int n) {
    __shared__ float w_lds[128];
    __shared__ int   s_lds[64];
    __shared__ float red[2][4];
    int node = blockIdx.x;
    int t = threadIdx.x;
    int wid = t >> 6;
    int beg = row_ptr[node], end = row_ptr[node + 1];
    int h_ch = t >> 6;
    float advv = ad1[node * 2 + (t & 1)];
    float acc0 = 0.f, acc1 = 0.f, ssum = 0.f;
    for (int base = beg; base < end; base += 64) {
        int cnt = min(64, end - base);
        int i = t >> 1, h = t & 1;
        if (i < cnt) {
            int s = edge_src[base + i];
            float e = as1[s * 2 + h] + advv;
            e = (e > 0.f) ? e : NEG_SLOPE * e;
            w_lds[i * 2 + h] = __expf(e);
            if (h == 0) s_lds[i] = s;
        }
        __syncthreads();
        #pragma unroll 4
        for (int i2 = 0; i2 < cnt; ++i2) {
            float wv = w_lds[i2 * 2 + h_ch];
            int s = s_lds[i2];
            unsigned p = *(const unsigned*)(h1h + (size_t)s * 256 + t * 2);
            _Float16 lo16 = __builtin_bit_cast(_Float16, (ushort_t)(p & 0xffffu));
            _Float16 hi16 = __builtin_bit_cast(_Float16, (ushort_t)(p >> 16));
            acc0 += wv * (float)lo16;
            acc1 += wv * (float)hi16;
            ssum += wv;
        }
        __syncthreads();
    }
    float inv = 1.f / (ssum + 1e-16f);
    float o0 = acc0 * inv + b1[t * 2];
    float o1 = acc1 * inv + b1[t * 2 + 1];
    o0 = (o0 > 0.f) ? o0 : (__expf(o0) - 1.f);
    o1 = (o1 > 0.f) ? o1 : (__expf(o1) - 1.f);
    float4 w0 = *(const float4*)(W2 + t * 8);
    float4 w1 = *(const float4*)(W2 + t * 8 + 4);
    float p0 = o0 * w0.x + o1 * w1.x;
    float p1 = o0 * w0.y + o1 * w1.y;
    float p2 = o0 * w0.z + o1 * w1.z;
    float p3 = o0 * w0.w + o1 * w1.w;
    #pragma unroll
    for (int off = 1; off < 64; off <<= 1) {
        p0 += __shfl_xor(p0, off, 64);
        p1 += __shfl_xor(p1, off, 64);
        p2 += __shfl_xor(p2, off, 64);
        p3 += __shfl_xor(p3, off, 64);
    }
    if ((t & 63) == 0) {
        red[wid][0] = p0; red[wid][1] = p1; red[wid][2] = p2; red[wid][3] = p3;
    }
    __syncthreads();
    if (t == 0) {
        float hv[4], s2 = 0.f, d2 = 0.f;
        #pragma unroll
        for (int j = 0; j < 4; ++j) {
            hv[j] = red[0][j] + red[1][j];
            h2[node * 4 + j] = hv[j];
            s2 += hv[j] * a_src2[j];
            d2 += hv[j] * a_dst2[j];
        }
        as2[node] = s2;
        ad2[node] = d2;
    }
}

// ---------------------------------------------------------------------------
// Aggregation layer 2 (1 head, C=4): wave per node, 16 edges in flight.
// ---------------------------------------------------------------------------
__global__ __launch_bounds__(256) void kagg2(const float* __restrict__ h2,
                                             const float* __restrict__ as2,
                                             const float* __restrict__ ad2,
                                             const float* __restrict__ b2,
                                             const int* __restrict__ row_ptr,
                                             const int* __restrict__ edge_src,
                                             float* __restrict__ out, int n) {
    int wid = threadIdx.x >> 6, lane = threadIdx.x & 63;
    int node = blockIdx.x * 4 + wid;
    if (node >= n) return;
    int beg = row_ptr[node], end = row_ptr[node + 1];
    int j = lane & 3, ig = lane >> 2;
    float adv = ad2[node];
    float acc = 0.f, ssum = 0.f;
    for (int p = beg + ig; p < end; p += 16) {
        int s = edge_src[p];
        float e = as2[s] + adv;
        e = (e > 0.f) ? e : NEG_SLOPE * e;
        float wv = __expf(e);
        acc += wv * h2[s * 4 + j];
        ssum += wv;
    }
    #pragma unroll
    for (int off = 32; off >= 4; off >>= 1) {
        acc += __shfl_down(acc, off);
        ssum += __shfl_down(ssum, off);
    }
    if (lane < 4) out[node * 4 + j] = acc / (ssum + 1e-16f) + b2[j];
}

// ---------------------------------------------------------------------------
extern "C" void kernel_launch(void* const* d_in, const int* in_sizes, int n_in,
                              void* d_out, int out_size, void* d_ws, size_t ws_size,
                              hipStream_t stream) {
    const float* x      = (const float*)d_in[0];
    const int*   ei     = (const int*)d_in[1];
    const float* W_pre  = (const float*)d_in[2];
    const float* b_pre  = (const float*)d_in[3];
    const float* W1     = (const float*)d_in[4];
    const float* a_src1 = (const float*)d_in[5];
    const float* a_dst1 = (const float*)d_in[6];
    const float* b1     = (const float*)d_in[7];
    const float* W2     = (const float*)d_in[8];
    const float* a_src2 = (const float*)d_in[9];
    const float* a_dst2 = (const float*)d_in[10];
    const float* b2     = (const float*)d_in[11];
    float* out = (float*)d_out;

    const int DIN = 1024;
    const int E = in_sizes[1] / 2;
    const int N = in_sizes[0] / DIN;

    const int* esrc = ei;
    const int* edst = ei + E;

    char* ws = (char*)d_ws;
    size_t off = 0;
    ushort_t* h1h = (ushort_t*)(ws + off); off += (size_t)N * 256 * 2;
    ushort_t* h0h = (ushort_t*)(ws + off); off += (size_t)N * 128 * 2;
    float* as1 = (float*)(ws + off);  off += (size_t)N * 2 * 4;
    float* ad1 = (float*)(ws + off);  off += (size_t)N * 2 * 4;
    float* h2  = (float*)(ws + off);  off += (size_t)N * 4 * 4;
    float* as2 = (float*)(ws + off);  off += (size_t)N * 4;
    float* ad2 = (float*)(ws + off);  off += (size_t)N * 4;
    int* row_ptr = (int*)(ws + off);  off += ((size_t)N + 16) * 4;
    int* cursor  = (int*)(ws + off);  off += (size_t)N * 4;
    int* counts  = (int*)(ws + off);  off += (size_t)N * 4;
    int* bsum    = (int*)(ws + off);  off += 64 * 4;
    int* boff    = (int*)(ws + off);  off += 64 * 4;
    int* edge_src = (int*)(ws + off); off += (size_t)(E + N) * 4;
    ushort_t* PreF = (ushort_t*)(ws + off); off += 1024 * 128 * 2;
    ushort_t* W1h  = (ushort_t*)(ws + off); off += 128 * 256 * 2;

    int G = (N + 1023) / 1024;

    // --- L0: zero counts ---
    hipMemsetAsync(counts, 0, (size_t)N * 4, stream);

    // --- L1: dst histogram ∪ weight prep (independent, concurrent) ---
    int HB = (E + 255) / 256;
    kl1<<<HB + 640, 256, 0, stream>>>(edst, E, counts, W_pre, W1, PreF, W1h, HB);

    // --- parallel scan (coalesced, multi-block) ---
    kscan_part<<<G, 1024, 0, stream>>>(counts, row_ptr, bsum, N);
    kscan_tops<<<1, 64, 0, stream>>>(bsum, boff, row_ptr, G, N);
    kscan_add<<<(N + 255) / 256, 256, 0, stream>>>(row_ptr, boff, cursor, N);

    // --- GEMM1: h0h = relu(x @ W_pre + b_pre) ---
    int Mb32 = (N + 31) / 32;
    kgemm_mfma1<<<Mb32, 256, 0, stream>>>(x, PreF, b_pre, h0h, N);

    // --- L3: CSR fill ∪ GEMM2+alpha1 (independent, concurrent) ---
    int FB = (E + N + 255) / 256;
    int Mb = (N + 63) / 64;
    kl3<<<FB + 2 * Mb, 256, 0, stream>>>(esrc, edst, E, N, cursor, edge_src, FB,
                                         h0h, W1h, a_src1, a_dst1, h1h, as1, ad1, N);

    // --- aggregate layer 1 + bias + elu + layer-2 linear + alpha2 (fused) ---
    kagg1<<<N, 128, 0, stream>>>(h1h, as1, ad1, b1, W2, a_src2, a_dst2,
                                 row_ptr, edge_src, h2, as2, ad2, N);
    // --- aggregate layer 2 + bias -> out ---
    kagg2<<<(N + 3) / 4, 256, 0, stream>>>(h2, as2, ad2, b2, row_ptr, edge_src, out, N);
}

// Round 7
// 507.175 us; speedup vs baseline: 1.2020x; 1.0408x over previous
//
#include <hip/hip_runtime.h>
#include <hip/hip_bf16.h>

#define NEG_SLOPE 0.2f

typedef _Float16 f16x8 __attribute__((ext_vector_type(8)));
typedef _Float16 f16x4 __attribute__((ext_vector_type(4)));
typedef float f32x4 __attribute__((ext_vector_type(4)));
typedef unsigned short ushort_t;

#define AS_GLOBAL(p) ((const __attribute__((address_space(1))) void*)(p))
#define AS_SHARED(p) ((__attribute__((address_space(3))) void*)(p))

__device__ inline f16x4 cvt4(float4 v) {
    f16x4 r;
    r[0] = (_Float16)v.x; r[1] = (_Float16)v.y;
    r[2] = (_Float16)v.z; r[3] = (_Float16)v.w;
    return r;
}

// ---------------------------------------------------------------------------
// L1: dst-histogram (blocks [0,HB)) ∪ weight prep (blocks [HB,HB+640)).
// W_pre/W1 -> fp16, swizzled to MFMA-B-frag order:
// elem (k,n) -> ((k>>3)*Nn + n)*8 + (k&7).
// ---------------------------------------------------------------------------
__global__ __launch_bounds__(256) void kl1(const int* __restrict__ edst, int E,
                                           int* __restrict__ counts,
                                           const float* __restrict__ Wpre,
                                           const float* __restrict__ W1,
                                           ushort_t* __restrict__ PreF,
                                           ushort_t* __restrict__ W1h, int HB) {
    int b = blockIdx.x, t = threadIdx.x;
    if (b < HB) {
        int i = b * 256 + t;
        if (i < E) atomicAdd(&counts[edst[i]], 1);
    } else {
        int i = (b - HB) * 256 + t;
        if (i < 1024 * 128) {
            int k = i >> 7, n = i & 127;
            int d = ((k >> 3) * 128 + n) * 8 + (k & 7);
            PreF[d] = __builtin_bit_cast(ushort_t, (_Float16)Wpre[i]);
        } else if (i < 1024 * 128 + 128 * 256) {
            int j2 = i - 1024 * 128;
            int k = j2 >> 8, n = j2 & 255;
            int d = ((k >> 3) * 256 + n) * 8 + (k & 7);
            W1h[d] = __builtin_bit_cast(ushort_t, (_Float16)W1[j2]);
        }
    }
}

// ---------------------------------------------------------------------------
// Scan stage 1: per-1024-block exclusive prefix of (counts[i]+1) + block sums.
// ---------------------------------------------------------------------------
__global__ __launch_bounds__(1024) void kscan_part(const int* __restrict__ counts,
                                                   int* __restrict__ row_ptr,
                                                   int* __restrict__ bsum, int n) {
    __shared__ int wsum[16];
    int t = threadIdx.x, lane = t & 63, wid = t >> 6;
    int i = blockIdx.x * 1024 + t;
    int v = (i < n) ? (counts[i] + 1) : 0;
    int x = v;
    #pragma unroll
    for (int off = 1; off < 64; off <<= 1) {
        int y = __shfl_up(x, off, 64);
        if (lane >= off) x += y;
    }
    if (lane == 63) wsum[wid] = x;
    __syncthreads();
    if (wid == 0) {
        int ws = (lane < 16) ? wsum[lane] : 0;
        #pragma unroll
        for (int off = 1; off < 16; off <<= 1) {
            int y = __shfl_up(ws, off, 64);
            if (lane >= off) ws += y;
        }
        if (lane < 16) wsum[lane] = ws;
    }
    __syncthreads();
    int wave_excl = (wid == 0) ? 0 : wsum[wid - 1];
    if (i < n) row_ptr[i] = wave_excl + (x - v);
    if (t == 0) bsum[blockIdx.x] = wsum[15];
}

// ---------------------------------------------------------------------------
// Scan stage 2 (fused tops+add): each 256-block covers one 1024-chunk slice;
// first wave reduces bsum[0..chunk) (G<=64), adds, writes row_ptr/cursor and
// the self-loop into slot 0 of each node's CSR segment (no atomic needed).
// Block 0 also writes row_ptr[n] = total.
// ---------------------------------------------------------------------------
__global__ __launch_bounds__(256) void kscan_add(int* __restrict__ row_ptr,
                                                 const int* __restrict__ bsum,
                                                 int* __restrict__ cursor,
                                                 int* __restrict__ edge_src,
                                                 int n, int G) {
    __shared__ int s_off;
    int t = threadIdx.x;
    int chunk = blockIdx.x >> 2;          // (blockIdx.x*256)>>10
    if (t < 64) {
        int v = (t < G && t < chunk) ? bsum[t] : 0;
        #pragma unroll
        for (int off = 32; off >= 1; off >>= 1) v += __shfl_down(v, off, 64);
        if (t == 0) s_off = v;
    }
    __syncthreads();
    int i = blockIdx.x * 256 + t;
    if (i < n) {
        int r = row_ptr[i] + s_off;
        row_ptr[i] = r;
        cursor[i] = r + 1;                // edges fill after the self-loop slot
        edge_src[r] = i;                  // self-loop at slot 0
    }
    if (blockIdx.x == 0 && t < 64) {
        int v = (t < G) ? bsum[t] : 0;
        #pragma unroll
        for (int off = 32; off >= 1; off >>= 1) v += __shfl_down(v, off, 64);
        if (t == 0) row_ptr[n] = v;
    }
}

// ---------------------------------------------------------------------------
// GEMM1: h0h(fp16) = relu(x @ W_pre + b_pre).  M x 1024 x 128.
// M-tile 32, 4 waves = 2 row-halves x 2 col-halves. A staged cooperatively:
// coalesced float4 loads -> fp16 cvt -> XOR-swizzled LDS (chunk c of row r
// stored at chunk (c ^ (r & 7))). B via global_load_lds (pre-swizzled).
// ---------------------------------------------------------------------------
__global__ __launch_bounds__(256) void kgemm_mfma1(const float* __restrict__ A,
                                                   const ushort_t* __restrict__ Bf,
                                                   const float* __restrict__ bias,
                                                   ushort_t* __restrict__ C, int M) {
    __shared__ __align__(16) ushort_t Bs[8192];   // 16 KB: B K-tile [kc8][n128][j8]
    __shared__ __align__(16) ushort_t As[2048];   // 4 KB: A tile 32x64 fp16, swizzled
    int t = threadIdx.x;
    int wid = t >> 6, lane = t & 63, q = lane >> 4, l15 = lane & 15;
    int wr = wid & 1, wc = wid >> 1;
    int m0 = blockIdx.x * 32;

    int ar = t >> 3, ac = t & 7;
    int srow = m0 + ar;
    if (srow >= M) srow = M - 1;
    const float* sA = A + (size_t)srow * 1024;
    int sw = ar & 7;                              // write-side XOR (row mod 8)
    int wadr0 = ar * 64 + (((ac >> 1)) ^ sw) * 8 + (ac & 1) * 4;
    int wadr1 = ar * 64 + ((4 + (ac >> 1)) ^ sw) * 8 + (ac & 1) * 4;

    float4 av[2][2];
    av[0][0] = *(const float4*)(sA + ac * 4);
    av[0][1] = *(const float4*)(sA + 32 + ac * 4);

    f32x4 acc[4];
    #pragma unroll
    for (int c = 0; c < 4; ++c) acc[c] = (f32x4){0.f, 0.f, 0.f, 0.f};

    int arow_rd = (wr * 16 + l15) * 64;
    int asw = l15 & 7;                            // read-side XOR (row mod 8)

    #pragma unroll 2
    for (int kt = 0; kt < 16; ++kt) {
        int cur = kt & 1, nxt = cur ^ 1;
        __syncthreads();
        {   // B-tile kt -> LDS (async DMA)
            const ushort_t* sF = Bf + kt * 8192;
            #pragma unroll
            for (int i = 0; i < 4; ++i) {
                int ge = (i * 256 + t) * 8;
                int le = (i * 256 + (t & 0xC0)) * 8;
                __builtin_amdgcn_global_load_lds(AS_GLOBAL(sF + ge), AS_SHARED(Bs + le), 16, 0, 0);
            }
        }
        if (kt < 15) {
            const float* a2 = sA + (kt + 1) * 64;
            av[nxt][0] = *(const float4*)(a2 + ac * 4);
            av[nxt][1] = *(const float4*)(a2 + 32 + ac * 4);
        }
        *(f16x4*)(As + wadr0) = cvt4(av[cur][0]);
        *(f16x4*)(As + wadr1) = cvt4(av[cur][1]);
        __syncthreads();
        #pragma unroll
        for (int ks = 0; ks < 2; ++ks) {
            int kc = ks * 4 + q;
            f16x8 af = *(const f16x8*)(As + arow_rd + ((kc ^ asw) * 8));
            #pragma unroll
            for (int c = 0; c < 4; ++c) {
                f16x8 b = *(const f16x8*)(Bs + (kc * 128 + wc * 64 + c * 16 + l15) * 8);
                acc[c] = __builtin_amdgcn_mfma_f32_16x16x32_f16(af, b, acc[c], 0, 0, 0);
            }
        }
    }
    #pragma unroll
    for (int c = 0; c < 4; ++c) {
        int n = wc * 64 + c * 16 + l15;
        float bv = bias[n];
        #pragma unroll
        for (int r = 0; r < 4; ++r) {
            int mm = m0 + wr * 16 + q * 4 + r;
            if (mm < M)
                C[(size_t)mm * 128 + n] =
                    __builtin_bit_cast(ushort_t, (_Float16)fmaxf(acc[c][r] + bv, 0.f));
        }
    }
}

// ---------------------------------------------------------------------------
// L3: CSR edge fill (blocks [0,FB)) ∪ GEMM2+alpha1 (blocks [FB, FB+2*Mb)).
// GEMM2: h1h(fp16) = h0h @ W1h, f16 MFMA; 64 rows x 128 cols per block,
// g = column half = head; fused as1/ad1 epilogue.
// ---------------------------------------------------------------------------
__global__ __launch_bounds__(256) void kl3(const int* __restrict__ esrc,
                                           const int* __restrict__ edst, int E,
                                           int* __restrict__ cursor,
                                           int* __restrict__ edge_src, int FB,
                                           const ushort_t* __restrict__ Ah,
                                           const ushort_t* __restrict__ W1h,
                                           const float* __restrict__ a_src,
                                           const float* __restrict__ a_dst,
                                           ushort_t* __restrict__ C,
                                           float* __restrict__ as1,
                                           float* __restrict__ ad1, int M) {
    __shared__ __align__(16) ushort_t Bs[16384];  // [kc16][n128][j8] fp16 = 32 KB
    int t = threadIdx.x;
    int b = blockIdx.x;
    if (b < FB) {
        int i = b * 256 + t;
        if (i < E) {
            int p = atomicAdd(&cursor[edst[i]], 1);
            edge_src[p] = esrc[i];
        }
        return;
    }
    int u = b - FB;
    int g = u & 1;
    int mblk = u >> 1;
    int wid = t >> 6, lane = t & 63;
    int q = lane >> 4, l15 = lane & 15;
    int m0 = mblk * 64 + wid * 16;
    int m = m0 + l15;
    const ushort_t* arow = Ah + (size_t)(m < M ? m : 0) * 128;

    {   // stage W1h half (cols g*128..+127)
        #pragma unroll
        for (int i = 0; i < 8; ++i) {
            int j = i * 4 + wid;
            int kc = j >> 1, hk = j & 1;
            int ge = ((kc * 256) + g * 128 + hk * 64 + lane) * 8;
            int le = j * 512;
            __builtin_amdgcn_global_load_lds(AS_GLOBAL(W1h + ge), AS_SHARED(Bs + le), 16, 0, 0);
        }
    }
    f16x8 af[4];
    #pragma unroll
    for (int ks = 0; ks < 4; ++ks)
        af[ks] = *(const f16x8*)(arow + ks * 32 + q * 8);
    __syncthreads();

    f32x4 acc[8];
    #pragma unroll
    for (int c = 0; c < 8; ++c) acc[c] = (f32x4){0.f, 0.f, 0.f, 0.f};

    #pragma unroll
    for (int ks = 0; ks < 4; ++ks) {
        int kc = ks * 4 + q;
        #pragma unroll
        for (int c = 0; c < 8; ++c) {
            f16x8 bfr = *(const f16x8*)(Bs + (kc * 128 + c * 16 + l15) * 8);
            acc[c] = __builtin_amdgcn_mfma_f32_16x16x32_f16(af[ks], bfr, acc[c], 0, 0, 0);
        }
    }
    #pragma unroll
    for (int c = 0; c < 8; ++c) {
        int nn = g * 128 + c * 16 + l15;
        #pragma unroll
        for (int r = 0; r < 4; ++r) {
            int mm = m0 + q * 4 + r;
            if (mm < M)
                C[(size_t)mm * 256 + nn] = __builtin_bit_cast(ushort_t, (_Float16)acc[c][r]);
        }
    }
    float asv[4] = {0.f, 0.f, 0.f, 0.f};
    float adv[4] = {0.f, 0.f, 0.f, 0.f};
    #pragma unroll
    for (int c = 0; c < 8; ++c) {
        float sa = a_src[g * 128 + c * 16 + l15];
        float da = a_dst[g * 128 + c * 16 + l15];
        #pragma unroll
        for (int r = 0; r < 4; ++r) {
            asv[r] += acc[c][r] * sa;
            adv[r] += acc[c][r] * da;
        }
    }
    #pragma unroll
    for (int off = 1; off <= 8; off <<= 1) {
        #pragma unroll
        for (int r = 0; r < 4; ++r) {
            asv[r] += __shfl_xor(asv[r], off, 64);
            adv[r] += __shfl_xor(adv[r], off, 64);
        }
    }
    if (l15 == 0) {
        #pragma unroll
        for (int r = 0; r < 4; ++r) {
            int node = m0 + q * 4 + r;
            if (node < M) {
                as1[node * 2 + g] = asv[r];
                ad1[node * 2 + g] = adv[r];
            }
        }
    }
}

// ---------------------------------------------------------------------------
// Aggregation layer 1 + fused layer-2 linear + alpha2.
// Wave-per-node, barrier-free, LDS-free; 8-deep gather ILP: per 32-edge
// batch, issue 8 row-gathers (static-indexed register array), then consume.
// OOB lanes clamp to row 0 (L1-resident) with weight 0.
// ---------------------------------------------------------------------------
__global__ __launch_bounds__(256) void kagg1(const ushort_t* __restrict__ h1h,
                                             const float* __restrict__ as1,
                                             const float* __restrict__ ad1,
                                             const float* __restrict__ b1,
                                             const float* __restrict__ W2,
                                             const float* __restrict__ a_src2,
                                             const float* __restrict__ a_dst2,
                                             const int* __restrict__ row_ptr,
                                             const int* __restrict__ edge_src,
                                             float* __restrict__ h2,
                                             float* __restrict__ as2,
                                             float* __restrict__ ad2, int n) {
    int wid = threadIdx.x >> 6, lane = threadIdx.x & 63;
    int node = blockIdx.x * 4 + wid;
    if (node >= n) return;
    int beg = row_ptr[node], end = row_ptr[node + 1];
    int h = lane >> 5;                       // head of my 4 channels
    float adv0 = ad1[node * 2];
    float adv1 = ad1[node * 2 + 1];
    float acc0 = 0.f, acc1 = 0.f, acc2 = 0.f, acc3 = 0.f, ssum = 0.f;
    for (int base = beg; base < end; base += 32) {
        int cnt = min(32, end - base);
        // lanes 2i / 2i+1 compute weights for edge i, heads 0/1
        float wv_mine = 0.f;
        int s_mine = 0;
        {
            int i = lane >> 1, hh = lane & 1;
            if (i < cnt) {
                s_mine = edge_src[base + i];
                float e = as1[s_mine * 2 + hh] + (hh ? adv1 : adv0);
                e = (e > 0.f) ? e : NEG_SLOPE * e;
                wv_mine = __expf(e);
            }
        }
        for (int i0 = 0; i0 < cnt; i0 += 8) {
            uint2 pv[8];
            float wv8[8];
            #pragma unroll
            for (int j = 0; j < 8; ++j) {
                int idx = i0 + j;                          // <= 31 always
                int sr = __shfl(s_mine, idx * 2, 64);
                float wr = __shfl(wv_mine, idx * 2 + h, 64);
                int ok = idx < cnt;
                int s = ok ? sr : 0;
                wv8[j] = ok ? wr : 0.f;
                pv[j] = *(const uint2*)(h1h + (size_t)s * 256 + lane * 4);
            }
            #pragma unroll
            for (int j = 0; j < 8; ++j) {
                float wv = wv8[j];
                acc0 += wv * (float)__builtin_bit_cast(_Float16, (ushort_t)(pv[j].x & 0xffffu));
                acc1 += wv * (float)__builtin_bit_cast(_Float16, (ushort_t)(pv[j].x >> 16));
                acc2 += wv * (float)__builtin_bit_cast(_Float16, (ushort_t)(pv[j].y & 0xffffu));
                acc3 += wv * (float)__builtin_bit_cast(_Float16, (ushort_t)(pv[j].y >> 16));
                ssum += wv;
            }
        }
    }
    float inv = 1.f / (ssum + 1e-16f);
    float o0 = acc0 * inv + b1[lane * 4 + 0];
    float o1 = acc1 * inv + b1[lane * 4 + 1];
    float o2 = acc2 * inv + b1[lane * 4 + 2];
    float o3 = acc3 * inv + b1[lane * 4 + 3];
    o0 = (o0 > 0.f) ? o0 : (__expf(o0) - 1.f);
    o1 = (o1 > 0.f) ? o1 : (__expf(o1) - 1.f);
    o2 = (o2 > 0.f) ? o2 : (__expf(o2) - 1.f);
    o3 = (o3 > 0.f) ? o3 : (__expf(o3) - 1.f);
    // fused linear: my 4 channels x W2 rows (lane*4 .. lane*4+3)
    float4 w0 = *(const float4*)(W2 + (lane * 4 + 0) * 4);
    float4 w1 = *(const float4*)(W2 + (lane * 4 + 1) * 4);
    float4 w2 = *(const float4*)(W2 + (lane * 4 + 2) * 4);
    float4 w3 = *(const float4*)(W2 + (lane * 4 + 3) * 4);
    float p0 = o0 * w0.x + o1 * w1.x + o2 * w2.x + o3 * w3.x;
    float p1 = o0 * w0.y + o1 * w1.y + o2 * w2.y + o3 * w3.y;
    float p2 = o0 * w0.z + o1 * w1.z + o2 * w2.z + o3 * w3.z;
    float p3 = o0 * w0.w + o1 * w1.w + o2 * w2.w + o3 * w3.w;
    #pragma unroll
    for (int off = 1; off < 64; off <<= 1) {
        p0 += __shfl_xor(p0, off, 64);
        p1 += __shfl_xor(p1, off, 64);
        p2 += __shfl_xor(p2, off, 64);
        p3 += __shfl_xor(p3, off, 64);
    }
    if (lane == 0) {
        h2[node * 4 + 0] = p0;
        h2[node * 4 + 1] = p1;
        h2[node * 4 + 2] = p2;
        h2[node * 4 + 3] = p3;
        as2[node] = p0 * a_src2[0] + p1 * a_src2[1] + p2 * a_src2[2] + p3 * a_src2[3];
        ad2[node] = p0 * a_dst2[0] + p1 * a_dst2[1] + p2 * a_dst2[2] + p3 * a_dst2[3];
    }
}

// ---------------------------------------------------------------------------
// Aggregation layer 2 (1 head, C=4): wave per node, 16 edges in flight.
// ---------------------------------------------------------------------------
__global__ __launch_bounds__(256) void kagg2(const float* __restrict__ h2,
                                             const float* __restrict__ as2,
                                             const float* __restrict__ ad2,
                                             const float* __restrict__ b2,
                                             const int* __restrict__ row_ptr,
                                             const int* __restrict__ edge_src,
                                             float* __restrict__ out, int n) {
    int wid = threadIdx.x >> 6, lane = threadIdx.x & 63;
    int node = blockIdx.x * 4 + wid;
    if (node >= n) return;
    int beg = row_ptr[node], end = row_ptr[node + 1];
    int j = lane & 3, ig = lane >> 2;
    float adv = ad2[node];
    float acc = 0.f, ssum = 0.f;
    for (int p = beg + ig; p < end; p += 16) {
        int s = edge_src[p];
        float e = as2[s] + adv;
        e = (e > 0.f) ? e : NEG_SLOPE * e;
        float wv = __expf(e);
        acc += wv * h2[s * 4 + j];
        ssum += wv;
    }
    #pragma unroll
    for (int off = 32; off >= 4; off >>= 1) {
        acc += __shfl_down(acc, off);
        ssum += __shfl_down(ssum, off);
    }
    if (lane < 4) out[node * 4 + j] = acc / (ssum + 1e-16f) + b2[j];
}

// ---------------------------------------------------------------------------
extern "C" void kernel_launch(void* const* d_in, const int* in_sizes, int n_in,
                              void* d_out, int out_size, void* d_ws, size_t ws_size,
                              hipStream_t stream) {
    const float* x      = (const float*)d_in[0];
    const int*   ei     = (const int*)d_in[1];
    const float* W_pre  = (const float*)d_in[2];
    const float* b_pre  = (const float*)d_in[3];
    const float* W1     = (const float*)d_in[4];
    const float* a_src1 = (const float*)d_in[5];
    const float* a_dst1 = (const float*)d_in[6];
    const float* b1     = (const float*)d_in[7];
    const float* W2     = (const float*)d_in[8];
    const float* a_src2 = (const float*)d_in[9];
    const float* a_dst2 = (const float*)d_in[10];
    const float* b2     = (const float*)d_in[11];
    float* out = (float*)d_out;

    const int DIN = 1024;
    const int E = in_sizes[1] / 2;
    const int N = in_sizes[0] / DIN;

    const int* esrc = ei;
    const int* edst = ei + E;

    char* ws = (char*)d_ws;
    size_t off = 0;
    ushort_t* h1h = (ushort_t*)(ws + off); off += (size_t)N * 256 * 2;
    ushort_t* h0h = (ushort_t*)(ws + off); off += (size_t)N * 128 * 2;
    float* as1 = (float*)(ws + off);  off += (size_t)N * 2 * 4;
    float* ad1 = (float*)(ws + off);  off += (size_t)N * 2 * 4;
    float* h2  = (float*)(ws + off);  off += (size_t)N * 4 * 4;
    float* as2 = (float*)(ws + off);  off += (size_t)N * 4;
    float* ad2 = (float*)(ws + off);  off += (size_t)N * 4;
    int* row_ptr = (int*)(ws + off);  off += ((size_t)N + 16) * 4;
    int* cursor  = (int*)(ws + off);  off += (size_t)N * 4;
    int* counts  = (int*)(ws + off);  off += (size_t)N * 4;
    int* bsum    = (int*)(ws + off);  off += 64 * 4;
    int* edge_src = (int*)(ws + off); off += (size_t)(E + N) * 4;
    ushort_t* PreF = (ushort_t*)(ws + off); off += 1024 * 128 * 2;
    ushort_t* W1h  = (ushort_t*)(ws + off); off += 128 * 256 * 2;

    int G = (N + 1023) / 1024;

    // --- L0: zero counts ---
    hipMemsetAsync(counts, 0, (size_t)N * 4, stream);

    // --- L1: dst histogram ∪ weight prep (independent, concurrent) ---
    int HB = (E + 255) / 256;
    kl1<<<HB + 640, 256, 0, stream>>>(edst, E, counts, W_pre, W1, PreF, W1h, HB);

    // --- scan (2 kernels; stage 2 also writes self-loops into CSR slot 0) ---
    kscan_part<<<G, 1024, 0, stream>>>(counts, row_ptr, bsum, N);
    kscan_add<<<(N + 255) / 256, 256, 0, stream>>>(row_ptr, bsum, cursor, edge_src, N, G);

    // --- GEMM1: h0h = relu(x @ W_pre + b_pre) ---
    int Mb32 = (N + 31) / 32;
    kgemm_mfma1<<<Mb32, 256, 0, stream>>>(x, PreF, b_pre, h0h, N);

    // --- L3: CSR edge fill ∪ GEMM2+alpha1 (independent, concurrent) ---
    int FB = (E + 255) / 256;
    int Mb = (N + 63) / 64;
    kl3<<<FB + 2 * Mb, 256, 0, stream>>>(esrc, edst, E, cursor, edge_src, FB,
                                         h0h, W1h, a_src1, a_dst1, h1h, as1, ad1, N);

    // --- aggregate layer 1 + bias + elu + layer-2 linear + alpha2 (fused) ---
    kagg1<<<(N + 3) / 4, 256, 0, stream>>>(h1h, as1, ad1, b1, W2, a_src2, a_dst2,
                                           row_ptr, edge_src, h2, as2, ad2, N);
    // --- aggregate layer 2 + bias -> out ---
    kagg2<<<(N + 3) / 4, 256, 0, stream>>>(h2, as2, ad2, b2, row_ptr, edge_src, out, N);
}